// Round 7
// baseline (694.641 us; speedup 1.0000x reference)
//
#include <hip/hip_runtime.h>
#include <stdint.h>

typedef unsigned short u16;
typedef __bf16 bf16x8 __attribute__((ext_vector_type(8)));
typedef float f32x4 __attribute__((ext_vector_type(4)));

#define LOG2E 1.4426950408889634f

__device__ __forceinline__ float bf2f(u16 a) {
  union { unsigned u; float f; } v; v.u = ((unsigned)a) << 16; return v.f;
}
__device__ __forceinline__ u16 f2bf(float f) {
  union { float f; unsigned u; } v; v.f = f;
  unsigned r = v.u + 0x7fffu + ((v.u >> 16) & 1u);
  return (u16)(r >> 16);
}
// async global->LDS, 16B/lane. LDS dest = wave-uniform base + lane*16.
__device__ __forceinline__ void gl_lds16(const void* g, void* l) {
  __builtin_amdgcn_global_load_lds(
      (const __attribute__((address_space(1))) uint32_t*)g,
      (__attribute__((address_space(3))) uint32_t*)l,
      16, 0, 0);
}

// ---------------------------------------------------------------------------
// GEMM: acc = A[M,K] @ Bt[N,K]^T  (bf16 in, fp32 accum), async LDS staging.
// BK=32, 4 waves 2x2, mfma 16x16x32 bf16.
// MODE: 0 bf16 C=acc | 1 bf16 C=acc+bias+res (o-proj, C may alias res)
//       2 bf16 C=relu(acc+bias) | 3 f32 C32=acc+bias+resx+bf2f(resbf)
//       4 f32 C32+=acc
// ---------------------------------------------------------------------------
template <int BM, int BN, int MODE>
__global__ __launch_bounds__(256) void gemm_bt(
    const u16* __restrict__ A, const u16* __restrict__ Bt,
    u16* Cbf, float* C32,
    const float* __restrict__ bias,
    const u16* resbf, const float* __restrict__ resx,
    int M, int N, int K)
{
  constexpr int MT = BM / 32, NT = BN / 32;
  constexpr int GA = (BM * 4) / 256, GB = (BN * 4) / 256;
  __shared__ u16 sA[BM * 32];
  __shared__ u16 sB[BN * 32];
  const int tid  = threadIdx.x;
  const int wave = tid >> 6, lane = tid & 63;
  const int quad = lane >> 4, l16 = lane & 15;
  const int wm = wave >> 1, wn = wave & 1;
  const int m0 = blockIdx.y * BM, n0 = blockIdx.x * BN;

  f32x4 acc[MT][NT] = {};

  for (int k0 = 0; k0 < K; k0 += 32) {
    __syncthreads();  // prev tile's LDS reads done
#pragma unroll
    for (int i = 0; i < GA; ++i) {
      int cb = i * 256 + wave * 64;   // wave-uniform LDS chunk base
      int c = cb + lane;
      int row = c >> 2, kc = c & 3;
      gl_lds16(A + (size_t)(m0 + row) * K + k0 + kc * 8, &sA[cb * 8]);
    }
#pragma unroll
    for (int i = 0; i < GB; ++i) {
      int cb = i * 256 + wave * 64;
      int c = cb + lane;
      int row = c >> 2, kc = c & 3;
      gl_lds16(Bt + (size_t)(n0 + row) * K + k0 + kc * 8, &sB[cb * 8]);
    }
    __syncthreads();  // barrier waitcnt drains vmcnt(0): staging complete

    bf16x8 fa[MT], fb[NT];
#pragma unroll
    for (int mt = 0; mt < MT; ++mt)
      fa[mt] = *(const bf16x8*)&sA[(wm * (BM / 2) + mt * 16 + l16) * 32 + quad * 8];
#pragma unroll
    for (int nt = 0; nt < NT; ++nt)
      fb[nt] = *(const bf16x8*)&sB[(wn * (BN / 2) + nt * 16 + l16) * 32 + quad * 8];
#pragma unroll
    for (int mt = 0; mt < MT; ++mt)
#pragma unroll
      for (int nt = 0; nt < NT; ++nt)
        acc[mt][nt] = __builtin_amdgcn_mfma_f32_16x16x32_bf16(
            fa[mt], fb[nt], acc[mt][nt], 0, 0, 0);
  }

  // epilogue: C layout col=lane&15, row=quad*4+reg
#pragma unroll
  for (int mt = 0; mt < MT; ++mt) {
#pragma unroll
    for (int nt = 0; nt < NT; ++nt) {
#pragma unroll
      for (int r = 0; r < 4; ++r) {
        int row = m0 + wm * (BM / 2) + mt * 16 + quad * 4 + r;
        int col = n0 + wn * (BN / 2) + nt * 16 + l16;
        size_t idx = (size_t)row * N + col;
        float v = acc[mt][nt][r];
        if constexpr (MODE == 0) {
          Cbf[idx] = f2bf(v);
        } else if constexpr (MODE == 1) {
          v += bias[col] + bf2f(resbf[idx]);
          Cbf[idx] = f2bf(v);
        } else if constexpr (MODE == 2) {
          v = fmaxf(v + bias[col], 0.f);
          Cbf[idx] = f2bf(v);
        } else if constexpr (MODE == 3) {
          v += bias[col] + resx[idx] + bf2f(resbf[idx]);
          C32[idx] = v;
        } else {
          C32[idx] = C32[idx] + v;
        }
      }
    }
  }
}

// ---------------------------------------------------------------------------
// 64x64-tiled transpose + fp32->bf16 cast: out[c][r] = (bf16)in[r][c].
// ---------------------------------------------------------------------------
__global__ __launch_bounds__(256) void transpose64(
    const float* __restrict__ in, u16* __restrict__ out, int R, int Cstride)
{
  __shared__ u16 tile[64][72];
  const int r0 = blockIdx.y * 64, c0 = blockIdx.x * 64;
  const int t = threadIdx.x;
  {
    const int lr = t >> 4, lc = (t & 15) * 4;
#pragma unroll
    for (int h = 0; h < 4; ++h) {
      int row = h * 16 + lr;
      float4 vd = *(const float4*)&in[(size_t)(r0 + row) * Cstride + c0 + lc];
      ushort4 ov;
      ov.x = f2bf(vd.x); ov.y = f2bf(vd.y); ov.z = f2bf(vd.z); ov.w = f2bf(vd.w);
      *(ushort4*)&tile[row][lc] = ov;
    }
  }
  __syncthreads();
  {
    const int lr = t >> 3, lv = t & 7;
#pragma unroll
    for (int h = 0; h < 2; ++h) {
      int orow = h * 32 + lr;
      u16 tmp[8];
#pragma unroll
      for (int j = 0; j < 8; ++j) tmp[j] = tile[lv * 8 + j][orow];
      *(uint4*)&out[(size_t)(c0 + orow) * R + r0 + lv * 8] = *(uint4*)tmp;
    }
  }
}

// ---------------------------------------------------------------------------
// V^T materialization: in = kvbuf v-half [b*1024+s][1024 + h*64 + d] (ld 2048)
// out vT[(b*16+h)*64 + d][s] (ld 1024). Grid (16 s-tiles, 64 bh).
// ---------------------------------------------------------------------------
__global__ __launch_bounds__(256) void vt_kernel(
    const u16* __restrict__ in, u16* __restrict__ out)
{
  __shared__ u16 tile[64][72];
  const int st = blockIdx.x, bh = blockIdx.y;
  const int b = bh >> 4, h = bh & 15;
  const int t = threadIdx.x;
  const int lr = t >> 3, lv = t & 7;
  const u16* src = in + ((size_t)b * 1024 + st * 64) * 2048 + 1024 + h * 64;
#pragma unroll
  for (int half = 0; half < 2; ++half) {
    int row = half * 32 + lr;
    uint4 vd = *(const uint4*)&src[(size_t)row * 2048 + lv * 8];
    *(uint4*)&tile[row][lv * 8] = vd;
  }
  __syncthreads();
  u16* dst = out + (size_t)bh * 64 * 1024 + st * 64;
#pragma unroll
  for (int half = 0; half < 2; ++half) {
    int orow = half * 32 + lr;
    u16 tmp[8];
#pragma unroll
    for (int j = 0; j < 8; ++j) tmp[j] = tile[lv * 8 + j][orow];
    *(uint4*)&dst[(size_t)orow * 1024 + lv * 8] = *(uint4*)tmp;
  }
}

// ---------------------------------------------------------------------------
// LayerNorm over D=1024, fp32 in -> bf16 out.
// ---------------------------------------------------------------------------
__global__ __launch_bounds__(256) void ln_kernel(
    const float* __restrict__ x, const float* __restrict__ g,
    const float* __restrict__ b, u16* __restrict__ outbf)
{
  const int row = blockIdx.x, t = threadIdx.x;
  const int wave = t >> 6, lane = t & 63;
  float4 xv = *(const float4*)&x[(size_t)row * 1024 + t * 4];
  float v0 = xv.x, v1 = xv.y, v2 = xv.z, v3 = xv.w;
  float s = v0 + v1 + v2 + v3;
  float s2 = v0 * v0 + v1 * v1 + v2 * v2 + v3 * v3;
  for (int m = 1; m < 64; m <<= 1) { s += __shfl_xor(s, m); s2 += __shfl_xor(s2, m); }
  __shared__ float ps[4], pq[4];
  if (lane == 0) { ps[wave] = s; pq[wave] = s2; }
  __syncthreads();
  s = ps[0] + ps[1] + ps[2] + ps[3];
  s2 = pq[0] + pq[1] + pq[2] + pq[3];
  float mean = s * (1.f / 1024.f);
  float var = s2 * (1.f / 1024.f) - mean * mean;
  float rs = rsqrtf(var + 1e-5f);
  float4 gv = *(const float4*)&g[t * 4];
  float4 bv = *(const float4*)&b[t * 4];
  ushort4 ov;
  ov.x = f2bf((v0 - mean) * rs * gv.x + bv.x);
  ov.y = f2bf((v1 - mean) * rs * gv.y + bv.y);
  ov.z = f2bf((v2 - mean) * rs * gv.z + bv.z);
  ov.w = f2bf((v3 - mean) * rs * gv.w + bv.w);
  *(ushort4*)&outbf[(size_t)row * 1024 + t * 4] = ov;
}

// h = LN(x + y), x fp32, y bf16.
__global__ __launch_bounds__(256) void ln_add_kernel(
    const float* __restrict__ x, const u16* __restrict__ ybf,
    const float* __restrict__ g, const float* __restrict__ b,
    u16* __restrict__ hbf)
{
  const int row = blockIdx.x, t = threadIdx.x;
  const int wave = t >> 6, lane = t & 63;
  float4 xv = *(const float4*)&x[(size_t)row * 1024 + t * 4];
  ushort4 yv = *(const ushort4*)&ybf[(size_t)row * 1024 + t * 4];
  float v0 = xv.x + bf2f(yv.x), v1 = xv.y + bf2f(yv.y);
  float v2 = xv.z + bf2f(yv.z), v3 = xv.w + bf2f(yv.w);
  float s = v0 + v1 + v2 + v3;
  float s2 = v0 * v0 + v1 * v1 + v2 * v2 + v3 * v3;
  for (int m = 1; m < 64; m <<= 1) { s += __shfl_xor(s, m); s2 += __shfl_xor(s2, m); }
  __shared__ float ps[4], pq[4];
  if (lane == 0) { ps[wave] = s; pq[wave] = s2; }
  __syncthreads();
  s = ps[0] + ps[1] + ps[2] + ps[3];
  s2 = pq[0] + pq[1] + pq[2] + pq[3];
  float mean = s * (1.f / 1024.f);
  float var = s2 * (1.f / 1024.f) - mean * mean;
  float rs = rsqrtf(var + 1e-5f);
  float4 gv = *(const float4*)&g[t * 4];
  float4 bv = *(const float4*)&b[t * 4];
  ushort4 ov;
  ov.x = f2bf((v0 - mean) * rs * gv.x + bv.x);
  ov.y = f2bf((v1 - mean) * rs * gv.y + bv.y);
  ov.z = f2bf((v2 - mean) * rs * gv.z + bv.z);
  ov.w = f2bf((v3 - mean) * rs * gv.w + bv.w);
  *(ushort4*)&hbf[(size_t)row * 1024 + t * 4] = ov;
}

// ---------------------------------------------------------------------------
// Flash-style cross-attention v3. Block = (64-q-tile, head, batch).
// - VGPR prefetch of K/Vt for chunk j+1 overlaps compute of chunk j.
// - Padded LDS (stride 72 elems = 144 B) kills fragment-read bank conflicts.
// - Static-max softmax in log2 domain: p = exp2(S*0.125*log2e + bias),
//   bias = -24 (unmasked, logits provably << 24) / -1e9 (masked -> p = 0).
//   No running max, no rescale, row-sum deferred to one post-loop reduction.
// ---------------------------------------------------------------------------
__global__ __launch_bounds__(256) void attn_kernel(
    const u16* __restrict__ Q,   // [b*1024+s1][1024], head offset h*64
    const u16* __restrict__ K,   // kvbuf [b*1024+s2][2048], head offset h*64
    const u16* __restrict__ Vt,  // [(b*16+h)*64+d][1024]
    const int* __restrict__ mask,
    u16* __restrict__ O)         // [b*1024+s1][1024]
{
  constexpr int LDP = 72;  // padded row stride, 144 B = 9*16 (16B-aligned rows)
  __shared__ u16 sQ[64 * LDP], sK[64 * LDP], sVt[64 * LDP], sP[64 * LDP];
  __shared__ float smaskb[64];
  const int qt = blockIdx.x, h = blockIdx.y, b = blockIdx.z;
  const int t = threadIdx.x;
  const int wave = t >> 6, lane = t & 63;
  const int quad = lane >> 4, l16 = lane & 15;
  const u16* Qb = Q + (size_t)b * 1024 * 1024 + (size_t)qt * 64 * 1024 + h * 64;
  const u16* Kb = K + (size_t)b * 1024 * 2048 + h * 64;
  const u16* Vb = Vt + (size_t)(b * 16 + h) * 64 * 1024;
  const float CSC = 0.125f * LOG2E;

  // stage Q into padded LDS
#pragma unroll
  for (int i = 0; i < 2; ++i) {
    int g = i * 256 + t, row = g >> 3, cc = g & 7;
    uint4 qv = *(const uint4*)&Qb[(size_t)row * 1024 + cc * 8];
    *(uint4*)&sQ[row * LDP + cc * 8] = qv;
  }

  // prefetch chunk j=0 into VGPRs
  uint4 kvv[2], vv[2];
#pragma unroll
  for (int i = 0; i < 2; ++i) {
    int g = i * 256 + t, row = g >> 3, cc = g & 7;
    kvv[i] = *(const uint4*)&Kb[(size_t)row * 2048 + cc * 8];
    vv[i]  = *(const uint4*)&Vb[(size_t)row * 1024 + cc * 8];
  }
  float mb = 0.f;
  if (t < 64) mb = (mask[b * 1024 + t] == 0) ? -1e9f : -24.0f;

  float lp[4] = {0.f, 0.f, 0.f, 0.f};
  f32x4 accO[4] = {};

  for (int j = 0; j < 16; ++j) {
    __syncthreads();  // prev iter's LDS reads done (covers sQ writes at j=0)
#pragma unroll
    for (int i = 0; i < 2; ++i) {
      int g = i * 256 + t, row = g >> 3, cc = g & 7;
      *(uint4*)&sK[row * LDP + cc * 8]  = kvv[i];
      *(uint4*)&sVt[row * LDP + cc * 8] = vv[i];
    }
    if (t < 64) smaskb[t] = mb;
    __syncthreads();  // staged
    // prefetch j+1 — latency hides behind QK+softmax+PV below
    if (j < 15) {
#pragma unroll
      for (int i = 0; i < 2; ++i) {
        int g = i * 256 + t, row = g >> 3, cc = g & 7;
        kvv[i] = *(const uint4*)&Kb[(size_t)((j + 1) * 64 + row) * 2048 + cc * 8];
        vv[i]  = *(const uint4*)&Vb[(size_t)row * 1024 + (j + 1) * 64 + cc * 8];
      }
      if (t < 64) mb = (mask[b * 1024 + (j + 1) * 64 + t] == 0) ? -1e9f : -24.0f;
    }

    // S = Q K^T : this wave's 16 q-rows x 64 s2-cols
    f32x4 accS[4] = {};
#pragma unroll
    for (int ks = 0; ks < 2; ++ks) {
      bf16x8 aq = *(const bf16x8*)&sQ[(wave * 16 + l16) * LDP + ks * 32 + quad * 8];
#pragma unroll
      for (int nt = 0; nt < 4; ++nt) {
        bf16x8 bk = *(const bf16x8*)&sK[(nt * 16 + l16) * LDP + ks * 32 + quad * 8];
        accS[nt] = __builtin_amdgcn_mfma_f32_16x16x32_bf16(aq, bk, accS[nt], 0, 0, 0);
      }
    }
    // static-max softmax (log2 domain); row = wave*16 + quad*4 + r
#pragma unroll
    for (int r = 0; r < 4; ++r) {
      float rsum = 0.f;
#pragma unroll
      for (int nt = 0; nt < 4; ++nt) {
        float p = exp2f(accS[nt][r] * CSC + smaskb[nt * 16 + l16]);
        rsum += p;
        sP[(wave * 16 + quad * 4 + r) * LDP + nt * 16 + l16] = f2bf(p);
      }
      lp[r] += rsum;
    }
    __syncthreads();  // sP visible
    // O += P @ V
#pragma unroll
    for (int ks = 0; ks < 2; ++ks) {
      bf16x8 ap = *(const bf16x8*)&sP[(wave * 16 + l16) * LDP + ks * 32 + quad * 8];
#pragma unroll
      for (int nt2 = 0; nt2 < 4; ++nt2) {
        bf16x8 bvv = *(const bf16x8*)&sVt[(nt2 * 16 + l16) * LDP + ks * 32 + quad * 8];
        accO[nt2] = __builtin_amdgcn_mfma_f32_16x16x32_bf16(ap, bvv, accO[nt2], 0, 0, 0);
      }
    }
  }

  // one deferred row-sum reduction (16 lanes within the quad-row group)
#pragma unroll
  for (int r = 0; r < 4; ++r) {
    float s = lp[r];
    for (int sh = 1; sh < 16; sh <<= 1) s += __shfl_xor(s, sh);
    lp[r] = 1.f / s;
  }
  u16* Ob = O + (size_t)b * 1024 * 1024 + (size_t)qt * 64 * 1024 + h * 64;
#pragma unroll
  for (int r = 0; r < 4; ++r) {
    int row = wave * 16 + quad * 4 + r;
#pragma unroll
    for (int nt2 = 0; nt2 < 4; ++nt2)
      Ob[(size_t)row * 1024 + nt2 * 16 + l16] = f2bf(accO[nt2][r] * lp[r]);
  }
}

// ---------------------------------------------------------------------------
extern "C" void kernel_launch(void* const* d_in, const int* in_sizes, int n_in,
                              void* d_out, int out_size, void* d_ws, size_t ws_size,
                              hipStream_t stream)
{
  const float* x   = (const float*)d_in[0];
  const float* kv  = (const float*)d_in[1];
  const int* attn_bias = (const int*)d_in[2];
  const float* ln1_g = (const float*)d_in[3];
  const float* ln1_b = (const float*)d_in[4];
  const float* qw0 = (const float*)d_in[5];
  const float* kw0 = (const float*)d_in[6];
  const float* vw0 = (const float*)d_in[7];
  const float* ow0 = (const float*)d_in[8];
  const float* ob0 = (const float*)d_in[9];
  const float* qw1 = (const float*)d_in[10];
  const float* kw1 = (const float*)d_in[11];
  const float* vw1 = (const float*)d_in[12];
  const float* ow1 = (const float*)d_in[13];
  const float* ob1 = (const float*)d_in[14];
  const float* ln2_g = (const float*)d_in[15];
  const float* ln2_b = (const float*)d_in[16];
  const float* w1 = (const float*)d_in[17];
  const float* b1 = (const float*)d_in[18];
  const float* w2 = (const float*)d_in[19];
  const float* b2 = (const float*)d_in[20];

  // ---- workspace: 48 MB peak (proven safe), d_out doubles as scratch ----
  char* ws = (char*)d_ws;
  const size_t MB = 1u << 20;
  u16* Wkv   = (u16*)(ws + 0 * MB);    // stacked kv weight-T [2048,1024] 4MB
  u16* Wsm   = (u16*)(ws + 4 * MB);    // q/o weight-T [1024,1024] 2MB (serial)
  u16* wtA   = (u16*)(ws + 0 * MB);    // FFN band w1-T [2048,1024] 4MB
  u16* wtB   = (u16*)(ws + 4 * MB);    // FFN band w2-T [1024,2048] 4MB
  u16* ybf   = (u16*)(ws + 8 * MB);    // residual y bf16 8MB
  u16* kvnbf = (u16*)(ws + 16 * MB);   // LN1(kv) 8MB; hbf aliases later
  u16* qbuf  = (u16*)(ws + 24 * MB);   // q bf16 8MB
  u16* kvbuf = (u16*)(ws + 32 * MB);   // [4096,2048] k|v 16MB; fbuf aliases
  u16* hbf   = kvnbf;
  u16* fbuf  = kvbuf;                  // [4096,2048] bf16 16MB
  u16* attnb = (u16*)d_out;                      // lower 8MB of d_out
  u16* vT    = (u16*)((char*)d_out + 8 * MB);    // upper 8MB of d_out
  float* out32 = (float*)d_out;

  const dim3 B256(256);
  const dim3 gT(16, 16);         // 1024x1024 weight transpose
  const dim3 gGemmN1k(8, 64);    // <64,128>  N=1024
  const dim3 gGemm2k(16, 32);    // <128,128> N=2048
  const dim3 gVt(16, 64);
  const dim3 gAttn(16, 16, 4);

  // --- LN1 ---
  ln_kernel<<<4096, B256, 0, stream>>>(x,  ln1_g, ln1_b, ybf);
  ln_kernel<<<4096, B256, 0, stream>>>(kv, ln1_g, ln1_b, kvnbf);

  for (int layer = 0; layer < 2; ++layer) {
    const float* qw = layer ? qw1 : qw0;
    const float* kw = layer ? kw1 : kw0;
    const float* vw = layer ? vw1 : vw0;
    const float* ow = layer ? ow1 : ow0;
    const float* ob = layer ? ob1 : ob0;

    // fused k|v projection: Wkv = [kw^T ; vw^T] (2048x1024)
    transpose64<<<gT, B256, 0, stream>>>(kw, Wkv, 1024, 1024);
    transpose64<<<gT, B256, 0, stream>>>(vw, Wkv + 1024 * 1024, 1024, 1024);
    gemm_bt<128, 128, 0><<<gGemm2k, B256, 0, stream>>>(
        kvnbf, Wkv, kvbuf, nullptr, nullptr, nullptr, nullptr, 4096, 2048, 1024);
    // q projection
    transpose64<<<gT, B256, 0, stream>>>(qw, Wsm, 1024, 1024);
    gemm_bt<64, 128, 0><<<gGemmN1k, B256, 0, stream>>>(
        ybf, Wsm, qbuf, nullptr, nullptr, nullptr, nullptr, 4096, 1024, 1024);
    // V^T materialization from kvbuf v-half
    vt_kernel<<<gVt, B256, 0, stream>>>(kvbuf, vT);

    attn_kernel<<<gAttn, B256, 0, stream>>>(qbuf, kvbuf, vT, attn_bias, attnb);

    // y = attn_out @ ow + ob + y
    transpose64<<<gT, B256, 0, stream>>>(ow, Wsm, 1024, 1024);
    gemm_bt<64, 128, 1><<<gGemmN1k, B256, 0, stream>>>(
        attnb, Wsm, ybf, nullptr, ob, ybf, nullptr, 4096, 1024, 1024);
  }

  // --- h = LN2(x + y) ---
  ln_add_kernel<<<4096, B256, 0, stream>>>(x, ybf, ln2_g, ln2_b, hbf);

  // --- FFN in two K-bands of 2048; fp32 accumulate into d_out ---
  for (int band = 0; band < 2; ++band) {
    transpose64<<<dim3(32, 16), B256, 0, stream>>>(w1 + band * 2048, wtA, 1024, 4096);
    transpose64<<<dim3(16, 32), B256, 0, stream>>>(w2 + (size_t)band * 2048 * 1024,
                                                   wtB, 2048, 1024);
    gemm_bt<128, 128, 2><<<gGemm2k, B256, 0, stream>>>(
        hbf, wtA, fbuf, nullptr, b1 + band * 2048, nullptr, nullptr,
        4096, 2048, 1024);
    if (band == 0) {
      gemm_bt<64, 128, 3><<<gGemmN1k, B256, 0, stream>>>(
          fbuf, wtB, nullptr, out32, b2, ybf, x, 4096, 1024, 2048);
    } else {
      gemm_bt<64, 128, 4><<<gGemmN1k, B256, 0, stream>>>(
          fbuf, wtB, nullptr, out32, nullptr, nullptr, nullptr, 4096, 1024, 2048);
    }
  }
}